// Round 4
// baseline (122.562 us; speedup 1.0000x reference)
//
#include <hip/hip_runtime.h>
#include <math.h>

// Additive (Bahdanau) attention. N=4, NQ=256, NV=512, NE=256, fp32.
// R4: 3 launches (prep=merged transposes, logits, epilogue QTB=4).
#define N_B   4
#define NQ_   256
#define NV_   512
#define NE_   256

// 2*log2(e): pre-scale q,c so sigma-term = rcp(1 + exp2(qs+cs))
#define QSCALE 2.8853900817779268f

__device__ __forceinline__ float wave_reduce_sum(float v) {
#pragma unroll
    for (int m = 32; m > 0; m >>= 1) v += __shfl_xor(v, m, 64);
    return v;
}

// ---- prep: C[n][v][e] -> CT[n][e][v] (scaled), and WR[e'][e] -> WRT[e][e'] ----
// blocks 0..127: C tiles (n = b>>5, e-tile = (b>>3)&3, v-tile = b&7)
// blocks 128..143: W tiles (r-tile = b>>2, c-tile = b&3)
__global__ __launch_bounds__(256) void prep_kernel(const float* __restrict__ C,
                                                   const float* __restrict__ W,
                                                   float* __restrict__ CT,
                                                   float* __restrict__ WT) {
    __shared__ float tile[64][65];
    const int b = blockIdx.x;
    const int col = threadIdx.x & 63, row4 = threadIdx.x >> 6;
    if (b < 128) {
        const int n  = b >> 5;
        const int e0 = ((b >> 3) & 3) * 64;
        const int v0 = (b & 7) * 64;
        const float* src = C + ((size_t)n * NV_ + v0) * NE_ + e0;
#pragma unroll
        for (int r = 0; r < 16; ++r) {
            const int vl = row4 + r * 4;
            tile[vl][col] = src[(size_t)vl * NE_ + col] * QSCALE;
        }
        __syncthreads();
        float* dst = CT + ((size_t)n * NE_ + e0) * NV_ + v0;
#pragma unroll
        for (int r = 0; r < 16; ++r) {
            const int el = row4 + r * 4;
            dst[(size_t)el * NV_ + col] = tile[col][el];
        }
    } else {
        const int bb = b - 128;
        const int r0 = (bb >> 2) * 64, c0 = (bb & 3) * 64;
        const float* src = W + (size_t)r0 * NE_ + c0;
#pragma unroll
        for (int r = 0; r < 16; ++r) {
            const int rl = row4 + r * 4;
            tile[rl][col] = src[(size_t)rl * NE_ + col];
        }
        __syncthreads();
        float* dst = WT + (size_t)c0 * NE_ + r0;
#pragma unroll
        for (int r = 0; r < 16; ++r) {
            const int cl = row4 + r * 4;
            dst[(size_t)cl * NE_ + col] = tile[col][cl];
        }
    }
}

// ---- kernel A: S[n][q][v] = sum_e w[e] * rcp(1+exp2(qs+cs)) ----
// block: 4 q-rows x 64 v; 4 waves split the e-range (64 e each).
// grid: (NV/64, NQ/4, N) = 2048 blocks -> 8 blocks/CU -> 100% occupancy.
#define QTA 4
__global__ __launch_bounds__(256, 8) void logits_kernel(
    const float* __restrict__ Q,   // [N][NQ][NE]
    const float* __restrict__ CT,  // [N][NE][NV] (pre-scaled)
    const float* __restrict__ WL,  // [NE]
    float* __restrict__ S)         // [N][NQ][NV]
{
    const int n  = blockIdx.z;
    const int q0 = blockIdx.y * QTA;
    const int v0 = blockIdx.x * 64;
    const int tid = threadIdx.x;
    const int wv = tid >> 6, ln = tid & 63;

    __shared__ __align__(16) float s_q[NE_][QTA];     // 4 KB
    __shared__ float s_w[NE_];                        // 1 KB
    __shared__ float s_part[4][QTA][64];              // 4 KB

    {   // preload q rows (scaled) + w_logit; thread == e
        const int e = tid;
        s_w[e] = WL[e];
#pragma unroll
        for (int j = 0; j < QTA; ++j)
            s_q[e][j] = Q[((size_t)n * NQ_ + q0 + j) * NE_ + e] * QSCALE;
    }
    __syncthreads();

    const float* ct = CT + (size_t)n * NE_ * NV_ + v0 + ln;
    float acc0 = 0.f, acc1 = 0.f, acc2 = 0.f, acc3 = 0.f;
    const int e0 = wv * 64;
#pragma unroll 4
    for (int e = e0; e < e0 + 64; ++e) {
        const float c = ct[(size_t)e * NV_];
        const float4 q4 = *(const float4*)s_q[e];
        const float w = s_w[e];
        acc0 = fmaf(w, __builtin_amdgcn_rcpf(1.0f + __builtin_amdgcn_exp2f(c + q4.x)), acc0);
        acc1 = fmaf(w, __builtin_amdgcn_rcpf(1.0f + __builtin_amdgcn_exp2f(c + q4.y)), acc1);
        acc2 = fmaf(w, __builtin_amdgcn_rcpf(1.0f + __builtin_amdgcn_exp2f(c + q4.z)), acc2);
        acc3 = fmaf(w, __builtin_amdgcn_rcpf(1.0f + __builtin_amdgcn_exp2f(c + q4.w)), acc3);
    }
    s_part[wv][0][ln] = acc0;
    s_part[wv][1][ln] = acc1;
    s_part[wv][2][ln] = acc2;
    s_part[wv][3][ln] = acc3;
    __syncthreads();

    {   // 4-way reduce + store; thread covers (j = tid>>6, lane = tid&63)
        const int j = tid >> 6, l = tid & 63;
        const float s = s_part[0][j][l] + s_part[1][j][l]
                      + s_part[2][j][l] + s_part[3][j][l];
        S[((size_t)n * NQ_ + q0 + j) * NV_ + v0 + l] = s;
    }
}

// ---- kernel B: softmax + PV + leaky_relu + output GEMM; block = (n, 4 q-rows) ----
#define QTB 4
#define NWB 8
__global__ __launch_bounds__(512) void attn_out(
    const float* __restrict__ S,     // [N][NQ][NV]
    const float* __restrict__ M,     // [N][NV][NE]
    const float* __restrict__ TEMP,
    const float* __restrict__ WRT,   // [NE][NE] = WR^T
    const float* __restrict__ BR,
    float* __restrict__ OUT)         // [N][NQ][NE]
{
    const int n  = blockIdx.y;
    const int q0 = blockIdx.x * QTB;
    const int tid = threadIdx.x;
    const int wv = tid >> 6, ln = tid & 63;

    __shared__ __align__(16) float s_prob[QTB][NV_];        // 8 KB
    __shared__ __align__(16) float s_part[NWB][QTB][NE_];   // 32 KB
    __shared__ __align__(16) float s_heads[QTB][NE_];       // 4 KB

    // softmax over v: wave w (w<4) handles q0+w (logit = -2*S/temp)
    if (wv < QTB) {
        const float scale = -2.0f / TEMP[0];
        const float* srow = S + ((size_t)n * NQ_ + q0 + wv) * NV_;
        float l[NV_ / 64];
        float mx = -1e30f;
#pragma unroll
        for (int k = 0; k < NV_ / 64; ++k) {
            l[k] = srow[ln + 64 * k] * scale;
            mx = fmaxf(mx, l[k]);
        }
#pragma unroll
        for (int m = 32; m > 0; m >>= 1) mx = fmaxf(mx, __shfl_xor(mx, m, 64));
        float sum = 0.0f;
#pragma unroll
        for (int k = 0; k < NV_ / 64; ++k) {
            l[k] = __expf(l[k] - mx);
            sum += l[k];
        }
        sum = wave_reduce_sum(sum);
        const float inv = 1.0f / sum;
#pragma unroll
        for (int k = 0; k < NV_ / 64; ++k) s_prob[wv][ln + 64 * k] = l[k] * inv;
    }
    __syncthreads();

    // PV: 8 waves partition v (64 each); lane = float4 of e
    {
        const float4* M4 = (const float4*)(M + (size_t)n * NV_ * NE_);
        float4 h[QTB];
#pragma unroll
        for (int t = 0; t < QTB; ++t) h[t] = make_float4(0.f, 0.f, 0.f, 0.f);
        const int v0 = wv * (NV_ / NWB);
#pragma unroll 2
        for (int v = v0; v < v0 + NV_ / NWB; ++v) {
            const float4 m = M4[v * (NE_ / 4) + ln];
#pragma unroll
            for (int t = 0; t < QTB; ++t) {
                const float p = s_prob[t][v];
                h[t].x = fmaf(p, m.x, h[t].x);
                h[t].y = fmaf(p, m.y, h[t].y);
                h[t].z = fmaf(p, m.z, h[t].z);
                h[t].w = fmaf(p, m.w, h[t].w);
            }
        }
#pragma unroll
        for (int t = 0; t < QTB; ++t) ((float4*)s_part[wv][t])[ln] = h[t];
    }
    __syncthreads();

    // reduce 8 wave-partials + leaky_relu (512 threads cover 4x256 in 2 passes)
#pragma unroll
    for (int i = tid; i < QTB * NE_; i += 512) {
        const int t = i >> 8, e = i & (NE_ - 1);
        float s = 0.0f;
#pragma unroll
        for (int w = 0; w < NWB; ++w) s += s_part[w][t][e];
        s_heads[t][e] = (s > 0.0f) ? s : 0.01f * s;
    }
    __syncthreads();

    // out[t][ep] = sum_e h[t][e]*WRT[e][ep] + BR[ep]; thread -> (2 rows, ep)
    {
        const int t0 = (tid >> 8) * 2;       // 0 or 2
        const int ep = tid & 255;
        const float* w = WRT + ep;
        float a0 = 0.f, a1 = 0.f;
#pragma unroll 8
        for (int e = 0; e < NE_; ++e) {
            const float wv_ = w[(size_t)e * NE_];
            a0 = fmaf(s_heads[t0][e], wv_, a0);
            a1 = fmaf(s_heads[t0 + 1][e], wv_, a1);
        }
        const float b = BR[ep];
        OUT[((size_t)n * NQ_ + q0 + t0) * NE_ + ep]     = a0 + b;
        OUT[((size_t)n * NQ_ + q0 + t0 + 1) * NE_ + ep] = a1 + b;
    }
}

extern "C" void kernel_launch(void* const* d_in, const int* in_sizes, int n_in,
                              void* d_out, int out_size, void* d_ws, size_t ws_size,
                              hipStream_t stream) {
    const float* Q  = (const float*)d_in[0];
    const float* C  = (const float*)d_in[1];
    const float* M  = (const float*)d_in[2];
    const float* WL = (const float*)d_in[3];
    // d_in[4] = b_logit: softmax shift-invariant -> unused.
    const float* T  = (const float*)d_in[5];
    const float* WR = (const float*)d_in[6];
    const float* BR = (const float*)d_in[7];
    float* OUT = (float*)d_out;

    float* CT  = (float*)d_ws;                        // N*NE*NV = 524288 floats
    float* WRT = CT + (size_t)N_B * NE_ * NV_;        // NE*NE   = 65536 floats
    float* S   = WRT + (size_t)NE_ * NE_;             // N*NQ*NV = 524288 floats
    // total ws: ~4.5 MB

    prep_kernel<<<dim3(128 + 16), 256, 0, stream>>>(C, WR, CT, WRT);

    dim3 ga(NV_ / 64, NQ_ / QTA, N_B);
    logits_kernel<<<ga, 256, 0, stream>>>(Q, CT, WL, S);

    dim3 gb(NQ_ / QTB, N_B);
    attn_out<<<gb, 512, 0, stream>>>(S, M, T, WRT, BR, OUT);
}

// Round 5
// 112.281 us; speedup vs baseline: 1.0916x; 1.0916x over previous
//
#include <hip/hip_runtime.h>
#include <math.h>

// Additive (Bahdanau) attention. N=4, NQ=256, NV=512, NE=256, fp32.
// R5: factor exp2(s(q+c)) = exp2(sq)*exp2(sc); hot loop = 1 rcp + 2 fma per element.
#define N_B   4
#define NQ_   256
#define NV_   512
#define NE_   256

// 2*log2(e): sigma-term = rcp(1 + exp2(s*q)*exp2(s*c))
#define QSCALE 2.8853900817779268f

__device__ __forceinline__ float wave_reduce_sum(float v) {
#pragma unroll
    for (int m = 32; m > 0; m >>= 1) v += __shfl_xor(v, m, 64);
    return v;
}

// ---- prep (160 blocks):
//   b 0..127  : EC[n][e][v] = exp2(QSCALE*C[n][v][e])   (transpose + exp2)
//   b 128..143: WRT[e][e'] = WR[e'][e]
//   b 144..159: EQ[n][q][e] = exp2(QSCALE*Q[n][q][e])   (element-wise)
__global__ __launch_bounds__(256) void prep_kernel(const float* __restrict__ C,
                                                   const float* __restrict__ W,
                                                   const float* __restrict__ Q,
                                                   float* __restrict__ EC,
                                                   float* __restrict__ WT,
                                                   float* __restrict__ EQ) {
    __shared__ float tile[64][65];
    const int b = blockIdx.x;
    const int col = threadIdx.x & 63, row4 = threadIdx.x >> 6;
    if (b < 128) {
        const int n  = b >> 5;
        const int e0 = ((b >> 3) & 3) * 64;
        const int v0 = (b & 7) * 64;
        const float* src = C + ((size_t)n * NV_ + v0) * NE_ + e0;
#pragma unroll
        for (int r = 0; r < 16; ++r) {
            const int vl = row4 + r * 4;
            tile[vl][col] = __builtin_amdgcn_exp2f(src[(size_t)vl * NE_ + col] * QSCALE);
        }
        __syncthreads();
        float* dst = EC + ((size_t)n * NE_ + e0) * NV_ + v0;
#pragma unroll
        for (int r = 0; r < 16; ++r) {
            const int el = row4 + r * 4;
            dst[(size_t)el * NV_ + col] = tile[col][el];
        }
    } else if (b < 144) {
        const int bb = b - 128;
        const int r0 = (bb >> 2) * 64, c0 = (bb & 3) * 64;
        const float* src = W + (size_t)r0 * NE_ + c0;
#pragma unroll
        for (int r = 0; r < 16; ++r) {
            const int rl = row4 + r * 4;
            tile[rl][col] = src[(size_t)rl * NE_ + col];
        }
        __syncthreads();
        float* dst = WT + (size_t)c0 * NE_ + r0;
#pragma unroll
        for (int r = 0; r < 16; ++r) {
            const int cl = row4 + r * 4;
            dst[(size_t)cl * NE_ + col] = tile[col][cl];
        }
    } else {
        // element-wise EQ over 262144 floats: 16 blocks x 256 thr x 16 float4
        const int bb = b - 144;
        const float4* q4 = (const float4*)Q;
        float4* eq4 = (float4*)EQ;
#pragma unroll
        for (int k = 0; k < 16; ++k) {
            const int i = bb * 4096 + k * 256 + threadIdx.x;  // float4 index
            float4 v = q4[i];
            v.x = __builtin_amdgcn_exp2f(v.x * QSCALE);
            v.y = __builtin_amdgcn_exp2f(v.y * QSCALE);
            v.z = __builtin_amdgcn_exp2f(v.z * QSCALE);
            v.w = __builtin_amdgcn_exp2f(v.w * QSCALE);
            eq4[i] = v;
        }
    }
}

// ---- kernel A: S[n][q][v] = sum_e w[e] * rcp(1 + EQ[q][e]*EC[e][v]) ----
// block: 4 q-rows x 64 v; 4 waves split the e-range (64 e each).
// grid: (NV/64, NQ/4, N) = 2048 blocks -> 8 blocks/CU -> 100% occupancy.
#define QTA 4
__global__ __launch_bounds__(256, 8) void logits_kernel(
    const float* __restrict__ EQ,  // [N][NQ][NE]
    const float* __restrict__ EC,  // [N][NE][NV]
    const float* __restrict__ WL,  // [NE]
    float* __restrict__ S)         // [N][NQ][NV]
{
    const int n  = blockIdx.z;
    const int q0 = blockIdx.y * QTA;
    const int v0 = blockIdx.x * 64;
    const int tid = threadIdx.x;
    const int wv = tid >> 6, ln = tid & 63;

    __shared__ __align__(16) float s_q[NE_][QTA];     // 4 KB
    __shared__ float s_w[NE_];                        // 1 KB
    __shared__ float s_part[4][QTA][64];              // 4 KB

    {   // preload EQ rows + w_logit; thread == e
        const int e = tid;
        s_w[e] = WL[e];
#pragma unroll
        for (int j = 0; j < QTA; ++j)
            s_q[e][j] = EQ[((size_t)n * NQ_ + q0 + j) * NE_ + e];
    }
    __syncthreads();

    const float* ec = EC + (size_t)n * NE_ * NV_ + v0 + ln;
    float acc0 = 0.f, acc1 = 0.f, acc2 = 0.f, acc3 = 0.f;
    const int e0 = wv * 64;
#pragma unroll 4
    for (int e = e0; e < e0 + 64; ++e) {
        const float c = ec[(size_t)e * NV_];
        const float4 q4 = *(const float4*)s_q[e];
        const float w = s_w[e];
        acc0 = fmaf(w, __builtin_amdgcn_rcpf(fmaf(c, q4.x, 1.0f)), acc0);
        acc1 = fmaf(w, __builtin_amdgcn_rcpf(fmaf(c, q4.y, 1.0f)), acc1);
        acc2 = fmaf(w, __builtin_amdgcn_rcpf(fmaf(c, q4.z, 1.0f)), acc2);
        acc3 = fmaf(w, __builtin_amdgcn_rcpf(fmaf(c, q4.w, 1.0f)), acc3);
    }
    s_part[wv][0][ln] = acc0;
    s_part[wv][1][ln] = acc1;
    s_part[wv][2][ln] = acc2;
    s_part[wv][3][ln] = acc3;
    __syncthreads();

    {   // 4-way reduce + store
        const int j = tid >> 6, l = tid & 63;
        const float s = s_part[0][j][l] + s_part[1][j][l]
                      + s_part[2][j][l] + s_part[3][j][l];
        S[((size_t)n * NQ_ + q0 + j) * NV_ + v0 + l] = s;
    }
}

// ---- kernel B: softmax + PV + leaky_relu + output GEMM; block = (n, 4 q-rows) ----
#define QTB 4
#define NWB 8
__global__ __launch_bounds__(512) void attn_out(
    const float* __restrict__ S,     // [N][NQ][NV]
    const float* __restrict__ M,     // [N][NV][NE]
    const float* __restrict__ TEMP,
    const float* __restrict__ WRT,   // [NE][NE] = WR^T
    const float* __restrict__ BR,
    float* __restrict__ OUT)         // [N][NQ][NE]
{
    const int n  = blockIdx.y;
    const int q0 = blockIdx.x * QTB;
    const int tid = threadIdx.x;
    const int wv = tid >> 6, ln = tid & 63;

    __shared__ __align__(16) float s_prob[QTB][NV_];        // 8 KB
    __shared__ __align__(16) float s_part[NWB][QTB][NE_];   // 32 KB
    __shared__ __align__(16) float s_heads[QTB][NE_];       // 4 KB

    // softmax over v: wave w (w<4) handles q0+w (logit = -2*S/temp)
    if (wv < QTB) {
        const float scale = -2.0f / TEMP[0];
        const float* srow = S + ((size_t)n * NQ_ + q0 + wv) * NV_;
        float l[NV_ / 64];
        float mx = -1e30f;
#pragma unroll
        for (int k = 0; k < NV_ / 64; ++k) {
            l[k] = srow[ln + 64 * k] * scale;
            mx = fmaxf(mx, l[k]);
        }
#pragma unroll
        for (int m = 32; m > 0; m >>= 1) mx = fmaxf(mx, __shfl_xor(mx, m, 64));
        float sum = 0.0f;
#pragma unroll
        for (int k = 0; k < NV_ / 64; ++k) {
            l[k] = __expf(l[k] - mx);
            sum += l[k];
        }
        sum = wave_reduce_sum(sum);
        const float inv = 1.0f / sum;
#pragma unroll
        for (int k = 0; k < NV_ / 64; ++k) s_prob[wv][ln + 64 * k] = l[k] * inv;
    }
    __syncthreads();

    // PV: 8 waves partition v (64 each); lane = float4 of e
    {
        const float4* M4 = (const float4*)(M + (size_t)n * NV_ * NE_);
        float4 h[QTB];
#pragma unroll
        for (int t = 0; t < QTB; ++t) h[t] = make_float4(0.f, 0.f, 0.f, 0.f);
        const int v0 = wv * (NV_ / NWB);
#pragma unroll 2
        for (int v = v0; v < v0 + NV_ / NWB; ++v) {
            const float4 m = M4[v * (NE_ / 4) + ln];
#pragma unroll
            for (int t = 0; t < QTB; ++t) {
                const float p = s_prob[t][v];
                h[t].x = fmaf(p, m.x, h[t].x);
                h[t].y = fmaf(p, m.y, h[t].y);
                h[t].z = fmaf(p, m.z, h[t].z);
                h[t].w = fmaf(p, m.w, h[t].w);
            }
        }
#pragma unroll
        for (int t = 0; t < QTB; ++t) ((float4*)s_part[wv][t])[ln] = h[t];
    }
    __syncthreads();

    // reduce 8 wave-partials + leaky_relu
#pragma unroll
    for (int i = tid; i < QTB * NE_; i += 512) {
        const int t = i >> 8, e = i & (NE_ - 1);
        float s = 0.0f;
#pragma unroll
        for (int w = 0; w < NWB; ++w) s += s_part[w][t][e];
        s_heads[t][e] = (s > 0.0f) ? s : 0.01f * s;
    }
    __syncthreads();

    // out[t][ep] = sum_e h[t][e]*WRT[e][ep] + BR[ep]
    {
        const int t0 = (tid >> 8) * 2;       // 0 or 2
        const int ep = tid & 255;
        const float* w = WRT + ep;
        float a0 = 0.f, a1 = 0.f;
#pragma unroll 8
        for (int e = 0; e < NE_; ++e) {
            const float wv_ = w[(size_t)e * NE_];
            a0 = fmaf(s_heads[t0][e], wv_, a0);
            a1 = fmaf(s_heads[t0 + 1][e], wv_, a1);
        }
        const float b = BR[ep];
        OUT[((size_t)n * NQ_ + q0 + t0) * NE_ + ep]     = a0 + b;
        OUT[((size_t)n * NQ_ + q0 + t0 + 1) * NE_ + ep] = a1 + b;
    }
}

extern "C" void kernel_launch(void* const* d_in, const int* in_sizes, int n_in,
                              void* d_out, int out_size, void* d_ws, size_t ws_size,
                              hipStream_t stream) {
    const float* Q  = (const float*)d_in[0];
    const float* C  = (const float*)d_in[1];
    const float* M  = (const float*)d_in[2];
    const float* WL = (const float*)d_in[3];
    // d_in[4] = b_logit: softmax shift-invariant -> unused.
    const float* T  = (const float*)d_in[5];
    const float* WR = (const float*)d_in[6];
    const float* BR = (const float*)d_in[7];
    float* OUT = (float*)d_out;

    float* EC  = (float*)d_ws;                        // N*NE*NV = 524288 floats
    float* WRT = EC + (size_t)N_B * NE_ * NV_;        // NE*NE   = 65536 floats
    float* S   = WRT + (size_t)NE_ * NE_;             // N*NQ*NV = 524288 floats
    float* EQ  = S + (size_t)N_B * NQ_ * NV_;         // N*NQ*NE = 262144 floats
    // total ws: ~5.5 MB

    prep_kernel<<<dim3(160), 256, 0, stream>>>(C, WR, Q, EC, WRT, EQ);

    dim3 ga(NV_ / 64, NQ_ / QTA, N_B);
    logits_kernel<<<ga, 256, 0, stream>>>(EQ, EC, WL, S);

    dim3 gb(NQ_ / QTB, N_B);
    attn_out<<<gb, 512, 0, stream>>>(S, M, T, WRT, BR, OUT);
}

// Round 6
// 109.148 us; speedup vs baseline: 1.1229x; 1.0287x over previous
//
#include <hip/hip_runtime.h>
#include <math.h>

// Additive (Bahdanau) attention. N=4, NQ=256, NV=512, NE=256, fp32.
// R6: paired-reciprocal logits (1 rcp / 2 elements); EQ folded into logits preload.
#define N_B   4
#define NQ_   256
#define NV_   512
#define NE_   256

// 2*log2(e): sigma-term = rcp(1 + exp2(s*q)*exp2(s*c))
#define QSCALE 2.8853900817779268f

__device__ __forceinline__ float wave_reduce_sum(float v) {
#pragma unroll
    for (int m = 32; m > 0; m >>= 1) v += __shfl_xor(v, m, 64);
    return v;
}

// ---- prep (144 blocks):
//   b 0..127  : EC[n][e][v] = exp2(QSCALE*C[n][v][e])   (transpose + exp2)
//   b 128..143: WRT[e][e'] = WR[e'][e]
__global__ __launch_bounds__(256) void prep_kernel(const float* __restrict__ C,
                                                   const float* __restrict__ W,
                                                   float* __restrict__ EC,
                                                   float* __restrict__ WT) {
    __shared__ float tile[64][65];
    const int b = blockIdx.x;
    const int col = threadIdx.x & 63, row4 = threadIdx.x >> 6;
    if (b < 128) {
        const int n  = b >> 5;
        const int e0 = ((b >> 3) & 3) * 64;
        const int v0 = (b & 7) * 64;
        const float* src = C + ((size_t)n * NV_ + v0) * NE_ + e0;
#pragma unroll
        for (int r = 0; r < 16; ++r) {
            const int vl = row4 + r * 4;
            tile[vl][col] = __builtin_amdgcn_exp2f(src[(size_t)vl * NE_ + col] * QSCALE);
        }
        __syncthreads();
        float* dst = EC + ((size_t)n * NE_ + e0) * NV_ + v0;
#pragma unroll
        for (int r = 0; r < 16; ++r) {
            const int el = row4 + r * 4;
            dst[(size_t)el * NV_ + col] = tile[col][el];
        }
    } else {
        const int bb = b - 128;
        const int r0 = (bb >> 2) * 64, c0 = (bb & 3) * 64;
        const float* src = W + (size_t)r0 * NE_ + c0;
#pragma unroll
        for (int r = 0; r < 16; ++r) {
            const int rl = row4 + r * 4;
            tile[rl][col] = src[(size_t)rl * NE_ + col];
        }
        __syncthreads();
        float* dst = WT + (size_t)c0 * NE_ + r0;
#pragma unroll
        for (int r = 0; r < 16; ++r) {
            const int cl = row4 + r * 4;
            dst[(size_t)cl * NE_ + col] = tile[col][cl];
        }
    }
}

// ---- kernel A: S[n][q][v] = sum_e w[e] * rcp(1 + EQ[q][e]*EC[e][v]) ----
// Paired over e: w0/a + w1/b = (w0*b + w1*a)*rcp(a*b); a,b in [1, 2^35] -> ab < 2^70, safe.
// block: 4 q-rows x 64 v; 4 waves split e (64 each). grid 2048 -> 8 blocks/CU.
#define QTA 4
__global__ __launch_bounds__(256, 8) void logits_kernel(
    const float* __restrict__ Q,   // [N][NQ][NE]
    const float* __restrict__ EC,  // [N][NE][NV]
    const float* __restrict__ WL,  // [NE]
    float* __restrict__ S)         // [N][NQ][NV]
{
    const int n  = blockIdx.z;
    const int q0 = blockIdx.y * QTA;
    const int v0 = blockIdx.x * 64;
    const int tid = threadIdx.x;
    const int wv = tid >> 6, ln = tid & 63;

    __shared__ __align__(16) float s_q[NE_][QTA];     // 4 KB  (exp2(s*q))
    __shared__ float s_w[NE_];                        // 1 KB
    __shared__ float s_part[4][QTA][64];              // 4 KB

    {   // preload: thread == e; EQ computed in-kernel
        const int e = tid;
        s_w[e] = WL[e];
#pragma unroll
        for (int j = 0; j < QTA; ++j)
            s_q[e][j] = __builtin_amdgcn_exp2f(
                Q[((size_t)n * NQ_ + q0 + j) * NE_ + e] * QSCALE);
    }
    __syncthreads();

    const float* ec = EC + (size_t)n * NE_ * NV_ + v0 + ln;
    float acc0 = 0.f, acc1 = 0.f, acc2 = 0.f, acc3 = 0.f;
    const int e0 = wv * 64;
#pragma unroll 4
    for (int e = e0; e < e0 + 64; e += 2) {
        const float c0 = ec[(size_t)e * NV_];
        const float c1 = ec[(size_t)(e + 1) * NV_];
        const float4 qa = *(const float4*)s_q[e];
        const float4 qb = *(const float4*)s_q[e + 1];
        const float w0 = s_w[e], w1 = s_w[e + 1];
        {   // q0
            const float a = fmaf(c0, qa.x, 1.0f);
            const float b = fmaf(c1, qb.x, 1.0f);
            const float num = fmaf(w1, a, w0 * b);
            acc0 = fmaf(num, __builtin_amdgcn_rcpf(a * b), acc0);
        }
        {   // q1
            const float a = fmaf(c0, qa.y, 1.0f);
            const float b = fmaf(c1, qb.y, 1.0f);
            const float num = fmaf(w1, a, w0 * b);
            acc1 = fmaf(num, __builtin_amdgcn_rcpf(a * b), acc1);
        }
        {   // q2
            const float a = fmaf(c0, qa.z, 1.0f);
            const float b = fmaf(c1, qb.z, 1.0f);
            const float num = fmaf(w1, a, w0 * b);
            acc2 = fmaf(num, __builtin_amdgcn_rcpf(a * b), acc2);
        }
        {   // q3
            const float a = fmaf(c0, qa.w, 1.0f);
            const float b = fmaf(c1, qb.w, 1.0f);
            const float num = fmaf(w1, a, w0 * b);
            acc3 = fmaf(num, __builtin_amdgcn_rcpf(a * b), acc3);
        }
    }
    s_part[wv][0][ln] = acc0;
    s_part[wv][1][ln] = acc1;
    s_part[wv][2][ln] = acc2;
    s_part[wv][3][ln] = acc3;
    __syncthreads();

    {   // 4-way reduce + store
        const int j = tid >> 6, l = tid & 63;
        const float s = s_part[0][j][l] + s_part[1][j][l]
                      + s_part[2][j][l] + s_part[3][j][l];
        S[((size_t)n * NQ_ + q0 + j) * NV_ + v0 + l] = s;
    }
}

// ---- kernel B: softmax + PV + leaky_relu + output GEMM; block = (n, 4 q-rows) ----
#define QTB 4
#define NWB 8
__global__ __launch_bounds__(512) void attn_out(
    const float* __restrict__ S,     // [N][NQ][NV]
    const float* __restrict__ M,     // [N][NV][NE]
    const float* __restrict__ TEMP,
    const float* __restrict__ WRT,   // [NE][NE] = WR^T
    const float* __restrict__ BR,
    float* __restrict__ OUT)         // [N][NQ][NE]
{
    const int n  = blockIdx.y;
    const int q0 = blockIdx.x * QTB;
    const int tid = threadIdx.x;
    const int wv = tid >> 6, ln = tid & 63;

    __shared__ __align__(16) float s_prob[QTB][NV_];        // 8 KB
    __shared__ __align__(16) float s_part[NWB][QTB][NE_];   // 32 KB
    __shared__ __align__(16) float s_heads[QTB][NE_];       // 4 KB

    // softmax over v: wave w (w<4) handles q0+w (logit = -2*S/temp)
    if (wv < QTB) {
        const float scale = -2.0f / TEMP[0];
        const float* srow = S + ((size_t)n * NQ_ + q0 + wv) * NV_;
        float l[NV_ / 64];
        float mx = -1e30f;
#pragma unroll
        for (int k = 0; k < NV_ / 64; ++k) {
            l[k] = srow[ln + 64 * k] * scale;
            mx = fmaxf(mx, l[k]);
        }
#pragma unroll
        for (int m = 32; m > 0; m >>= 1) mx = fmaxf(mx, __shfl_xor(mx, m, 64));
        float sum = 0.0f;
#pragma unroll
        for (int k = 0; k < NV_ / 64; ++k) {
            l[k] = __expf(l[k] - mx);
            sum += l[k];
        }
        sum = wave_reduce_sum(sum);
        const float inv = 1.0f / sum;
#pragma unroll
        for (int k = 0; k < NV_ / 64; ++k) s_prob[wv][ln + 64 * k] = l[k] * inv;
    }
    __syncthreads();

    // PV: 8 waves partition v (64 each); lane = float4 of e
    {
        const float4* M4 = (const float4*)(M + (size_t)n * NV_ * NE_);
        float4 h[QTB];
#pragma unroll
        for (int t = 0; t < QTB; ++t) h[t] = make_float4(0.f, 0.f, 0.f, 0.f);
        const int v0 = wv * (NV_ / NWB);
#pragma unroll 2
        for (int v = v0; v < v0 + NV_ / NWB; ++v) {
            const float4 m = M4[v * (NE_ / 4) + ln];
#pragma unroll
            for (int t = 0; t < QTB; ++t) {
                const float p = s_prob[t][v];
                h[t].x = fmaf(p, m.x, h[t].x);
                h[t].y = fmaf(p, m.y, h[t].y);
                h[t].z = fmaf(p, m.z, h[t].z);
                h[t].w = fmaf(p, m.w, h[t].w);
            }
        }
#pragma unroll
        for (int t = 0; t < QTB; ++t) ((float4*)s_part[wv][t])[ln] = h[t];
    }
    __syncthreads();

    // reduce 8 wave-partials + leaky_relu
#pragma unroll
    for (int i = tid; i < QTB * NE_; i += 512) {
        const int t = i >> 8, e = i & (NE_ - 1);
        float s = 0.0f;
#pragma unroll
        for (int w = 0; w < NWB; ++w) s += s_part[w][t][e];
        s_heads[t][e] = (s > 0.0f) ? s : 0.01f * s;
    }
    __syncthreads();

    // out[t][ep] = sum_e h[t][e]*WRT[e][ep] + BR[ep]
    {
        const int t0 = (tid >> 8) * 2;       // 0 or 2
        const int ep = tid & 255;
        const float* w = WRT + ep;
        float a0 = 0.f, a1 = 0.f;
#pragma unroll 8
        for (int e = 0; e < NE_; ++e) {
            const float wv_ = w[(size_t)e * NE_];
            a0 = fmaf(s_heads[t0][e], wv_, a0);
            a1 = fmaf(s_heads[t0 + 1][e], wv_, a1);
        }
        const float b = BR[ep];
        OUT[((size_t)n * NQ_ + q0 + t0) * NE_ + ep]     = a0 + b;
        OUT[((size_t)n * NQ_ + q0 + t0 + 1) * NE_ + ep] = a1 + b;
    }
}

extern "C" void kernel_launch(void* const* d_in, const int* in_sizes, int n_in,
                              void* d_out, int out_size, void* d_ws, size_t ws_size,
                              hipStream_t stream) {
    const float* Q  = (const float*)d_in[0];
    const float* C  = (const float*)d_in[1];
    const float* M  = (const float*)d_in[2];
    const float* WL = (const float*)d_in[3];
    // d_in[4] = b_logit: softmax shift-invariant -> unused.
    const float* T  = (const float*)d_in[5];
    const float* WR = (const float*)d_in[6];
    const float* BR = (const float*)d_in[7];
    float* OUT = (float*)d_out;

    float* EC  = (float*)d_ws;                        // N*NE*NV = 524288 floats
    float* WRT = EC + (size_t)N_B * NE_ * NV_;        // NE*NE   = 65536 floats
    float* S   = WRT + (size_t)NE_ * NE_;             // N*NQ*NV = 524288 floats
    // total ws: ~4.5 MB

    prep_kernel<<<dim3(144), 256, 0, stream>>>(C, WR, EC, WRT);

    dim3 ga(NV_ / 64, NQ_ / QTA, N_B);
    logits_kernel<<<ga, 256, 0, stream>>>(Q, EC, WL, S);

    dim3 gb(NQ_ / QTB, N_B);
    attn_out<<<gb, 512, 0, stream>>>(S, M, T, WRT, BR, OUT);
}

// Round 8
// 108.698 us; speedup vs baseline: 1.1275x; 1.0041x over previous
//
#include <hip/hip_runtime.h>
#include <math.h>

// Additive (Bahdanau) attention. N=4, NQ=256, NV=512, NE=256, fp32.
// R8 = R6 reverted (best passing: 109.1 us). R7's cooperative merge failed to
// launch (absmax 454 = stub signature -> hipLaunchCooperativeKernel rejected).
// Structure: prep (EC=exp2(s*C^T), WRT) | logits (paired-rcp) | epilogue.
#define N_B   4
#define NQ_   256
#define NV_   512
#define NE_   256

// 2*log2(e): sigma-term = rcp(1 + exp2(s*q)*exp2(s*c))
#define QSCALE 2.8853900817779268f

__device__ __forceinline__ float wave_reduce_sum(float v) {
#pragma unroll
    for (int m = 32; m > 0; m >>= 1) v += __shfl_xor(v, m, 64);
    return v;
}

// ---- prep (144 blocks):
//   b 0..127  : EC[n][e][v] = exp2(QSCALE*C[n][v][e])   (transpose + exp2)
//   b 128..143: WRT[e][e'] = WR[e'][e]
__global__ __launch_bounds__(256) void prep_kernel(const float* __restrict__ C,
                                                   const float* __restrict__ W,
                                                   float* __restrict__ EC,
                                                   float* __restrict__ WT) {
    __shared__ float tile[64][65];
    const int b = blockIdx.x;
    const int col = threadIdx.x & 63, row4 = threadIdx.x >> 6;
    if (b < 128) {
        const int n  = b >> 5;
        const int e0 = ((b >> 3) & 3) * 64;
        const int v0 = (b & 7) * 64;
        const float* src = C + ((size_t)n * NV_ + v0) * NE_ + e0;
#pragma unroll
        for (int r = 0; r < 16; ++r) {
            const int vl = row4 + r * 4;
            tile[vl][col] = __builtin_amdgcn_exp2f(src[(size_t)vl * NE_ + col] * QSCALE);
        }
        __syncthreads();
        float* dst = EC + ((size_t)n * NE_ + e0) * NV_ + v0;
#pragma unroll
        for (int r = 0; r < 16; ++r) {
            const int el = row4 + r * 4;
            dst[(size_t)el * NV_ + col] = tile[col][el];
        }
    } else {
        const int bb = b - 128;
        const int r0 = (bb >> 2) * 64, c0 = (bb & 3) * 64;
        const float* src = W + (size_t)r0 * NE_ + c0;
#pragma unroll
        for (int r = 0; r < 16; ++r) {
            const int rl = row4 + r * 4;
            tile[rl][col] = src[(size_t)rl * NE_ + col];
        }
        __syncthreads();
        float* dst = WT + (size_t)c0 * NE_ + r0;
#pragma unroll
        for (int r = 0; r < 16; ++r) {
            const int cl = row4 + r * 4;
            dst[(size_t)cl * NE_ + col] = tile[col][cl];
        }
    }
}

// ---- kernel A: S[n][q][v] = sum_e w[e] * rcp(1 + EQ[q][e]*EC[e][v]) ----
// Paired over e: w0/a + w1/b = (w0*b + w1*a)*rcp(a*b); a,b in [1, 2^35] -> ab < 2^70, safe.
// block: 4 q-rows x 64 v; 4 waves split e (64 each). grid 2048 -> 8 blocks/CU.
#define QTA 4
__global__ __launch_bounds__(256, 8) void logits_kernel(
    const float* __restrict__ Q,   // [N][NQ][NE]
    const float* __restrict__ EC,  // [N][NE][NV]
    const float* __restrict__ WL,  // [NE]
    float* __restrict__ S)         // [N][NQ][NV]
{
    const int n  = blockIdx.z;
    const int q0 = blockIdx.y * QTA;
    const int v0 = blockIdx.x * 64;
    const int tid = threadIdx.x;
    const int wv = tid >> 6, ln = tid & 63;

    __shared__ __align__(16) float s_q[NE_][QTA];     // 4 KB  (exp2(s*q))
    __shared__ float s_w[NE_];                        // 1 KB
    __shared__ float s_part[4][QTA][64];              // 4 KB

    {   // preload: thread == e; EQ computed in-kernel
        const int e = tid;
        s_w[e] = WL[e];
#pragma unroll
        for (int j = 0; j < QTA; ++j)
            s_q[e][j] = __builtin_amdgcn_exp2f(
                Q[((size_t)n * NQ_ + q0 + j) * NE_ + e] * QSCALE);
    }
    __syncthreads();

    const float* ec = EC + (size_t)n * NE_ * NV_ + v0 + ln;
    float acc0 = 0.f, acc1 = 0.f, acc2 = 0.f, acc3 = 0.f;
    const int e0 = wv * 64;
#pragma unroll 4
    for (int e = e0; e < e0 + 64; e += 2) {
        const float c0 = ec[(size_t)e * NV_];
        const float c1 = ec[(size_t)(e + 1) * NV_];
        const float4 qa = *(const float4*)s_q[e];
        const float4 qb = *(const float4*)s_q[e + 1];
        const float w0 = s_w[e], w1 = s_w[e + 1];
        {   // q0
            const float a = fmaf(c0, qa.x, 1.0f);
            const float b = fmaf(c1, qb.x, 1.0f);
            const float num = fmaf(w1, a, w0 * b);
            acc0 = fmaf(num, __builtin_amdgcn_rcpf(a * b), acc0);
        }
        {   // q1
            const float a = fmaf(c0, qa.y, 1.0f);
            const float b = fmaf(c1, qb.y, 1.0f);
            const float num = fmaf(w1, a, w0 * b);
            acc1 = fmaf(num, __builtin_amdgcn_rcpf(a * b), acc1);
        }
        {   // q2
            const float a = fmaf(c0, qa.z, 1.0f);
            const float b = fmaf(c1, qb.z, 1.0f);
            const float num = fmaf(w1, a, w0 * b);
            acc2 = fmaf(num, __builtin_amdgcn_rcpf(a * b), acc2);
        }
        {   // q3
            const float a = fmaf(c0, qa.w, 1.0f);
            const float b = fmaf(c1, qb.w, 1.0f);
            const float num = fmaf(w1, a, w0 * b);
            acc3 = fmaf(num, __builtin_amdgcn_rcpf(a * b), acc3);
        }
    }
    s_part[wv][0][ln] = acc0;
    s_part[wv][1][ln] = acc1;
    s_part[wv][2][ln] = acc2;
    s_part[wv][3][ln] = acc3;
    __syncthreads();

    {   // 4-way reduce + store
        const int j = tid >> 6, l = tid & 63;
        const float s = s_part[0][j][l] + s_part[1][j][l]
                      + s_part[2][j][l] + s_part[3][j][l];
        S[((size_t)n * NQ_ + q0 + j) * NV_ + v0 + l] = s;
    }
}

// ---- kernel B: softmax + PV + leaky_relu + output GEMM; block = (n, 4 q-rows) ----
#define QTB 4
#define NWB 8
__global__ __launch_bounds__(512) void attn_out(
    const float* __restrict__ S,     // [N][NQ][NV]
    const float* __restrict__ M,     // [N][NV][NE]
    const float* __restrict__ TEMP,
    const float* __restrict__ WRT,   // [NE][NE] = WR^T
    const float* __restrict__ BR,
    float* __restrict__ OUT)         // [N][NQ][NE]
{
    const int n  = blockIdx.y;
    const int q0 = blockIdx.x * QTB;
    const int tid = threadIdx.x;
    const int wv = tid >> 6, ln = tid & 63;

    __shared__ __align__(16) float s_prob[QTB][NV_];        // 8 KB
    __shared__ __align__(16) float s_part[NWB][QTB][NE_];   // 32 KB
    __shared__ __align__(16) float s_heads[QTB][NE_];       // 4 KB

    // softmax over v: wave w (w<4) handles q0+w (logit = -2*S/temp)
    if (wv < QTB) {
        const float scale = -2.0f / TEMP[0];
        const float* srow = S + ((size_t)n * NQ_ + q0 + wv) * NV_;
        float l[NV_ / 64];
        float mx = -1e30f;
#pragma unroll
        for (int k = 0; k < NV_ / 64; ++k) {
            l[k] = srow[ln + 64 * k] * scale;
            mx = fmaxf(mx, l[k]);
        }
#pragma unroll
        for (int m = 32; m > 0; m >>= 1) mx = fmaxf(mx, __shfl_xor(mx, m, 64));
        float sum = 0.0f;
#pragma unroll
        for (int k = 0; k < NV_ / 64; ++k) {
            l[k] = __expf(l[k] - mx);
            sum += l[k];
        }
        sum = wave_reduce_sum(sum);
        const float inv = 1.0f / sum;
#pragma unroll
        for (int k = 0; k < NV_ / 64; ++k) s_prob[wv][ln + 64 * k] = l[k] * inv;
    }
    __syncthreads();

    // PV: 8 waves partition v (64 each); lane = float4 of e
    {
        const float4* M4 = (const float4*)(M + (size_t)n * NV_ * NE_);
        float4 h[QTB];
#pragma unroll
        for (int t = 0; t < QTB; ++t) h[t] = make_float4(0.f, 0.f, 0.f, 0.f);
        const int v0 = wv * (NV_ / NWB);
#pragma unroll 2
        for (int v = v0; v < v0 + NV_ / NWB; ++v) {
            const float4 m = M4[v * (NE_ / 4) + ln];
#pragma unroll
            for (int t = 0; t < QTB; ++t) {
                const float p = s_prob[t][v];
                h[t].x = fmaf(p, m.x, h[t].x);
                h[t].y = fmaf(p, m.y, h[t].y);
                h[t].z = fmaf(p, m.z, h[t].z);
                h[t].w = fmaf(p, m.w, h[t].w);
            }
        }
#pragma unroll
        for (int t = 0; t < QTB; ++t) ((float4*)s_part[wv][t])[ln] = h[t];
    }
    __syncthreads();

    // reduce 8 wave-partials + leaky_relu
#pragma unroll
    for (int i = tid; i < QTB * NE_; i += 512) {
        const int t = i >> 8, e = i & (NE_ - 1);
        float s = 0.0f;
#pragma unroll
        for (int w = 0; w < NWB; ++w) s += s_part[w][t][e];
        s_heads[t][e] = (s > 0.0f) ? s : 0.01f * s;
    }
    __syncthreads();

    // out[t][ep] = sum_e h[t][e]*WRT[e][ep] + BR[ep]
    {
        const int t0 = (tid >> 8) * 2;       // 0 or 2
        const int ep = tid & 255;
        const float* w = WRT + ep;
        float a0 = 0.f, a1 = 0.f;
#pragma unroll 8
        for (int e = 0; e < NE_; ++e) {
            const float wv_ = w[(size_t)e * NE_];
            a0 = fmaf(s_heads[t0][e], wv_, a0);
            a1 = fmaf(s_heads[t0 + 1][e], wv_, a1);
        }
        const float b = BR[ep];
        OUT[((size_t)n * NQ_ + q0 + t0) * NE_ + ep]     = a0 + b;
        OUT[((size_t)n * NQ_ + q0 + t0 + 1) * NE_ + ep] = a1 + b;
    }
}

extern "C" void kernel_launch(void* const* d_in, const int* in_sizes, int n_in,
                              void* d_out, int out_size, void* d_ws, size_t ws_size,
                              hipStream_t stream) {
    const float* Q  = (const float*)d_in[0];
    const float* C  = (const float*)d_in[1];
    const float* M  = (const float*)d_in[2];
    const float* WL = (const float*)d_in[3];
    // d_in[4] = b_logit: softmax shift-invariant -> unused.
    const float* T  = (const float*)d_in[5];
    const float* WR = (const float*)d_in[6];
    const float* BR = (const float*)d_in[7];
    float* OUT = (float*)d_out;

    float* EC  = (float*)d_ws;                        // N*NE*NV = 524288 floats
    float* WRT = EC + (size_t)N_B * NE_ * NV_;        // NE*NE   = 65536 floats
    float* S   = WRT + (size_t)NE_ * NE_;             // N*NQ*NV = 524288 floats
    // total ws: ~4.5 MB

    prep_kernel<<<dim3(144), 256, 0, stream>>>(C, WR, EC, WRT);

    dim3 ga(NV_ / 64, NQ_ / QTA, N_B);
    logits_kernel<<<ga, 256, 0, stream>>>(Q, EC, WL, S);

    dim3 gb(NQ_ / QTB, N_B);
    attn_out<<<gb, 512, 0, stream>>>(S, M, T, WRT, BR, OUT);
}